// Round 5
// baseline (633.112 us; speedup 1.0000x reference)
//
#include <hip/hip_runtime.h>

#define HEADS 6
#define N_TOK 144
#define DIM   192
#define NW    64
#define NB    15
#define NBW   (NB * NW)          // 960
#define CHUNK 480                // bw per chunk (2 chunks)

typedef __attribute__((ext_vector_type(8))) short bf16x8;
typedef __attribute__((ext_vector_type(4))) float f32x4;

#define MFMA(a, b, c) __builtin_amdgcn_mfma_f32_16x16x32_bf16(a, b, c, 0, 0, 0)

static __device__ __forceinline__ short f2bf(float f) {
    union { float f; unsigned u; } v; v.f = f;
    unsigned r = v.u + 0x7FFFu + ((v.u >> 16) & 1u);   // RNE
    return (short)(r >> 16);
}
static __device__ __forceinline__ float bf2f(short s) {
    union { unsigned u; float f; } v;
    v.u = ((unsigned)(unsigned short)s) << 16;
    return v.f;
}
static __device__ __forceinline__ unsigned pk2(float a, float b) {
    return (unsigned)(unsigned short)f2bf(a) |
           ((unsigned)(unsigned short)f2bf(b) << 16);
}

// ---------------------------------------------------------------------------
// K0a: bias gather -> bf16, layout [(w*6+h)][i*144+j].
// ---------------------------------------------------------------------------
__global__ __launch_bounds__(256)
void bias_k(const float* __restrict__ table, const int* __restrict__ pos_index,
            short* __restrict__ bias_bf) {
    const int t = blockIdx.x;                      // w*6+h, 0..383
    for (int e = threadIdx.x; e < N_TOK * N_TOK; e += 256) {
        int idx = pos_index[e];
        bias_bf[(long)t * (N_TOK * N_TOK) + e] = f2bf(table[(long)idx * 384 + t]);
    }
}

// K0b: f32 -> bf16 copy (weights)
__global__ __launch_bounds__(256)
void cvt_k(const float* __restrict__ w, short* __restrict__ o, int n) {
    int i = blockIdx.x * 256 + threadIdx.x;
    if (i < n) o[i] = f2bf(w[i]);
}

// ---------------------------------------------------------------------------
// K1: QKV GEMM, block = bw. A-frags: f32 x from global, converted in-reg.
// B-frags: L2-resident bf16 qkv_w. 9 waves = 3 mg x 3 sel; wave = 48 rows x
// 192 cols (one sel). Epilogues:
//   v (sel==2): write V^T directly to vT_ws[bwL][h][e][row] (short4, 8B).
//   q,k: 2 rounds of LDS restage [144][200] -> coalesced bf16x8 stores.
// q pre-scaled by 32^-0.5.
// ---------------------------------------------------------------------------
__global__ __launch_bounds__(576)
void qkvs2_k(const float* __restrict__ x, const short* __restrict__ qkvw_bf,
             const float* __restrict__ qkv_b, short* __restrict__ qk_ws,
             short* __restrict__ vT_ws, int bw0) {
    __shared__ short outst[N_TOK * 200];   // 57,600 B
    const int bwL = blockIdx.x;
    const int bwG = bw0 + bwL;
    const int tid = threadIdx.x;
    const int wid = tid >> 6, lane = tid & 63, lq = lane & 15, lg = lane >> 4;
    const int mg = wid / 3, sel = wid % 3;
    const float* xg = x + (long)bwG * N_TOK * DIM;

    f32x4 acc[3][12] = {};
    for (int ks = 0; ks < 6; ++ks) {
        const int k0 = ks * 32 + 8 * lg;
        bf16x8 av[3];
        #pragma unroll
        for (int mt = 0; mt < 3; ++mt) {
            const float4* p = (const float4*)&xg[(mg * 48 + mt * 16 + lq) * DIM + k0];
            float4 f0 = p[0], f1 = p[1];
            bf16x8 a;
            a[0] = f2bf(f0.x); a[1] = f2bf(f0.y); a[2] = f2bf(f0.z); a[3] = f2bf(f0.w);
            a[4] = f2bf(f1.x); a[5] = f2bf(f1.y); a[6] = f2bf(f1.z); a[7] = f2bf(f1.w);
            av[mt] = a;
        }
        #pragma unroll
        for (int nt = 0; nt < 12; ++nt) {
            bf16x8 bv = *(const bf16x8*)&qkvw_bf[(sel * 192 + nt * 16 + lq) * 192 + k0];
            #pragma unroll
            for (int mt = 0; mt < 3; ++mt)
                acc[mt][nt] = MFMA(av[mt], bv, acc[mt][nt]);
        }
    }

    const float scale = 0.17677669529663687f;   // 32^-0.5

    // ---- v epilogue: direct V^T stores ----
    if (sel == 2) {
        #pragma unroll
        for (int nt = 0; nt < 12; ++nt) {
            const int cd = nt * 16 + lq;
            const float bb = qkv_b[2 * 192 + cd];
            const int h = cd >> 5, e = cd & 31;
            short* vp = vT_ws + ((long)(bwL * 6 + h) * 32 + e) * N_TOK;
            #pragma unroll
            for (int mt = 0; mt < 3; ++mt) {
                short4 s = { f2bf(acc[mt][nt][0] + bb), f2bf(acc[mt][nt][1] + bb),
                             f2bf(acc[mt][nt][2] + bb), f2bf(acc[mt][nt][3] + bb) };
                *(short4*)&vp[mg * 48 + mt * 16 + 4 * lg] = s;
            }
        }
    }

    // ---- q,k epilogue: LDS restage rounds ----
    for (int r = 0; r < 2; ++r) {
        __syncthreads();
        if (sel == r) {
            #pragma unroll
            for (int nt = 0; nt < 12; ++nt) {
                const int cd = nt * 16 + lq;
                const float bb = qkv_b[r * 192 + cd];
                #pragma unroll
                for (int mt = 0; mt < 3; ++mt)
                    #pragma unroll
                    for (int i = 0; i < 4; ++i) {
                        float v = acc[mt][nt][i] + bb;
                        if (r == 0) v *= scale;
                        outst[(mg * 48 + mt * 16 + 4 * lg + i) * 200 + cd] = f2bf(v);
                    }
            }
        }
        __syncthreads();
        short* dst = qk_ws + (long)bwL * 6 * 2 * 4608;
        #pragma unroll
        for (int j = 0; j < 6; ++j) {
            int u = (j * 576 + tid) * 8;            // 0..27647
            int h = u / 4608, rem = u - h * 4608;
            int row = rem >> 5, e = rem & 31;
            *(bf16x8*)&dst[((long)h * 2 + r) * 4608 + row * 32 + e] =
                *(const bf16x8*)&outst[row * 200 + h * 32 + e];
        }
    }
}

// ---------------------------------------------------------------------------
// K2: attention, block = (bwL, head), 9 waves x 16 query rows.
// Swapped QK^T: lgt = mfma(K, Q) -> lane holds S[k=nt*16+4lg+i][q=m0+lq]:
// bias (short4) + mask (float4) vector loads, softmax with 2 shuffles,
// P packed u32 -> per-wave streaming LDS buffer [16][40], PV = mfma(V^T, P).
// ---------------------------------------------------------------------------
__global__ __launch_bounds__(576)
void attn2_k(const short* __restrict__ qk_ws, const short* __restrict__ vT_ws,
             const short* __restrict__ bias_bf, const float* __restrict__ mask,
             short* __restrict__ tmp, int bw0) {
    __shared__ short vlds[32 * 152];      //  9,728 B
    __shared__ short pws[9 * 16 * 40];    // 11,520 B

    const int bid = blockIdx.x;
    const int h   = bid % HEADS;
    const int bwL = bid / HEADS;
    const int bwG = bw0 + bwL;
    const int tid = threadIdx.x;
    const int lane = tid & 63, lq = lane & 15, lg = lane >> 4;
    const int wid = tid >> 6;
    const int m0 = wid * 16;
    const int w = bwG & 63;

    // stage V^T -> vlds [32][152]: one 16B load + one 16B LDS write per thread
    {
        const short* vsrc = vT_ws + (long)(bwL * 6 + h) * 4608;
        int e = tid / 18, k0 = (tid % 18) * 8;
        bf16x8 v = *(const bf16x8*)&vsrc[e * N_TOK + k0];
        *(bf16x8*)&vlds[e * 152 + k0] = v;
    }
    __syncthreads();

    const short* qb = qk_ws + (long)(bwL * 6 + h) * 2 * 4608;
    const short* kb = qb + 4608;

    // ---- QK^T (swapped: A=K tile, B=Q tile) ----
    const f32x4 zf = {};
    bf16x8 bq = *(const bf16x8*)&qb[(m0 + lq) * 32 + 8 * lg];
    f32x4 lgt[9];
    #pragma unroll
    for (int nt = 0; nt < 9; ++nt) {
        bf16x8 ak = *(const bf16x8*)&kb[(nt * 16 + lq) * 32 + 8 * lg];
        lgt[nt] = MFMA(ak, bq, zf);
    }

    // ---- + bias + mask (vectorized: q row fixed = m0+lq) ----
    const short* bp = bias_bf + (long)(w * 6 + h) * (N_TOK * N_TOK) + (m0 + lq) * N_TOK;
    const float* mp = mask + (long)bwG * (N_TOK * N_TOK) + (m0 + lq) * N_TOK;
    #pragma unroll
    for (int nt = 0; nt < 9; ++nt) {
        int kbase = nt * 16 + 4 * lg;
        short4 bs = *(const short4*)&bp[kbase];
        float4 mf = *(const float4*)&mp[kbase];
        lgt[nt][0] += bf2f(bs.x) + mf.x;
        lgt[nt][1] += bf2f(bs.y) + mf.y;
        lgt[nt][2] += bf2f(bs.z) + mf.z;
        lgt[nt][3] += bf2f(bs.w) + mf.w;
    }

    // ---- softmax over k (36 in-lane + lanes xor16/xor32) ----
    float m = lgt[0][0];
    #pragma unroll
    for (int nt = 0; nt < 9; ++nt)
        #pragma unroll
        for (int i = 0; i < 4; ++i) m = fmaxf(m, lgt[nt][i]);
    m = fmaxf(m, __shfl_xor(m, 16));
    m = fmaxf(m, __shfl_xor(m, 32));
    float s = 0.f;
    #pragma unroll
    for (int nt = 0; nt < 9; ++nt)
        #pragma unroll
        for (int i = 0; i < 4; ++i) {
            float p = __expf(lgt[nt][i] - m);
            lgt[nt][i] = p;
            s += p;
        }
    s += __shfl_xor(s, 16);
    s += __shfl_xor(s, 32);
    const float inv = 1.f / s;

    // ---- PV: stream P (packed bf16 pairs) through per-wave LDS [16][40] ----
    short* pw = pws + wid * 16 * 40;
    f32x4 o[2] = {};
    const bf16x8 zb = {};
    #pragma unroll
    for (int kt = 0; kt < 5; ++kt) {
        const int nt0 = 2 * kt;
        *(unsigned*)&pw[lq * 40 + 4 * lg]     = pk2(lgt[nt0][0], lgt[nt0][1]);
        *(unsigned*)&pw[lq * 40 + 4 * lg + 2] = pk2(lgt[nt0][2], lgt[nt0][3]);
        if (kt < 4) {
            const int nt1 = nt0 + 1;
            *(unsigned*)&pw[lq * 40 + 16 + 4 * lg]     = pk2(lgt[nt1][0], lgt[nt1][1]);
            *(unsigned*)&pw[lq * 40 + 16 + 4 * lg + 2] = pk2(lgt[nt1][2], lgt[nt1][3]);
        }
        bf16x8 bpf = *(const bf16x8*)&pw[lq * 40 + 8 * lg];
        #pragma unroll
        for (int et = 0; et < 2; ++et) {
            bf16x8 av = *(const bf16x8*)&vlds[(et * 16 + lq) * 152 + kt * 32 + 8 * lg];
            bf16x8 aa = av, bb = bpf;
            if (kt == 4 && lg >= 2) { aa = zb; bb = zb; }   // keys 144..159
            o[et] = MFMA(aa, bb, o[et]);
        }
    }

    // ---- write tmp[bwL][q][h*32 + e] (short4, 8B) ----
    short* tb = tmp + (long)bwL * N_TOK * DIM + (m0 + lq) * DIM + h * 32;
    #pragma unroll
    for (int et = 0; et < 2; ++et) {
        short4 sx = { f2bf(o[et][0] * inv), f2bf(o[et][1] * inv),
                      f2bf(o[et][2] * inv), f2bf(o[et][3] * inv) };
        *(short4*)&tb[et * 16 + 4 * lg] = sx;
    }
}

// ---------------------------------------------------------------------------
// K3: output projection. Block = (bwL, m-third), 3 waves, wave = 16 rows.
// A from tmp bf16 (16B loads), B from L2-resident bf16 proj_w. No LDS.
// ---------------------------------------------------------------------------
__global__ __launch_bounds__(192)
void proj_k(const short* __restrict__ tmp, const short* __restrict__ pwt,
            const float* __restrict__ proj_b, float* __restrict__ out, int bw0) {
    const int bid = blockIdx.x;
    const int mthird = bid % 3;
    const int bwL = bid / 3;
    const int bwG = bw0 + bwL;
    const int tid = threadIdx.x;
    const int wid = tid >> 6, lane = tid & 63, lq = lane & 15, lg = lane >> 4;
    const int m0 = (mthird * 3 + wid) * 16;
    const short* tb = tmp + (long)bwL * N_TOK * DIM;

    f32x4 acc[12] = {};
    for (int ks = 0; ks < 6; ++ks) {
        const int k0 = ks * 32 + 8 * lg;
        bf16x8 a = *(const bf16x8*)&tb[(m0 + lq) * DIM + k0];
        #pragma unroll
        for (int nt = 0; nt < 12; ++nt) {
            bf16x8 b = *(const bf16x8*)&pwt[(nt * 16 + lq) * DIM + k0];
            acc[nt] = MFMA(a, b, acc[nt]);
        }
    }
    float* ob = out + (long)bwG * N_TOK * DIM;
    #pragma unroll
    for (int nt = 0; nt < 12; ++nt) {
        float pb = proj_b[nt * 16 + lq];
        #pragma unroll
        for (int i = 0; i < 4; ++i)
            ob[(m0 + 4 * lg + i) * DIM + nt * 16 + lq] = acc[nt][i] + pb;
    }
}

// ---------------------------------------------------------------------------
extern "C" void kernel_launch(void* const* d_in, const int* in_sizes, int n_in,
                              void* d_out, int out_size, void* d_ws, size_t ws_size,
                              hipStream_t stream) {
    const float* x        = (const float*)d_in[0];
    const float* mask     = (const float*)d_in[1];
    const float* qkv_w    = (const float*)d_in[2];
    const float* qkv_b    = (const float*)d_in[3];
    const float* table    = (const float*)d_in[4];
    const float* proj_w   = (const float*)d_in[5];
    const float* proj_b   = (const float*)d_in[6];
    const int*   pos_index= (const int*)d_in[7];
    float* out = (float*)d_out;

    // ws layout (bf16 shorts), total 122.39 MB (== R4's proven footprint):
    //  bias_bf  [384][144*144]              15.93 MB
    //  projw_bf [192*192]                    0.07 MB
    //  qkvw_bf  [576*192]                    0.22 MB
    //  qk_ws    [CHUNK*6][2][144][32]       53.08 MB (per chunk)
    //  vT_ws    [CHUNK*6][32][144]          26.54 MB (per chunk)
    //  tmp_ws   [CHUNK][144][192]           26.54 MB (per chunk)
    short* bias_bf  = (short*)d_ws;
    short* projw_bf = bias_bf + (size_t)384 * N_TOK * N_TOK;
    short* qkvw_bf  = projw_bf + 36864;
    short* qk_ws    = qkvw_bf + 110592;
    short* vT_ws    = qk_ws + (size_t)CHUNK * 6 * 2 * 4608;
    short* tmp_ws   = vT_ws + (size_t)CHUNK * 6 * 4608;

    bias_k<<<384, 256, 0, stream>>>(table, pos_index, bias_bf);
    cvt_k<<<144, 256, 0, stream>>>(proj_w, projw_bf, DIM * DIM);
    cvt_k<<<432, 256, 0, stream>>>(qkv_w, qkvw_bf, 3 * DIM * DIM);

    for (int c = 0; c < 2; ++c) {
        const int bw0 = c * CHUNK;
        qkvs2_k<<<CHUNK, 576, 0, stream>>>(x, qkvw_bf, qkv_b, qk_ws, vT_ws, bw0);
        attn2_k<<<CHUNK * 6, 576, 0, stream>>>(qk_ws, vT_ws, bias_bf, mask,
                                               tmp_ws, bw0);
        proj_k<<<CHUNK * 3, 192, 0, stream>>>(tmp_ws, projw_bf, proj_b, out, bw0);
    }
}

// Round 6
// 439.989 us; speedup vs baseline: 1.4389x; 1.4389x over previous
//
#include <hip/hip_runtime.h>

#define HEADS 6
#define N_TOK 144
#define DIM   192
#define NW    64
#define NB    15
#define NBW   (NB * NW)          // 960
#define CHUNK 480                // bw per chunk (2 chunks)

typedef __attribute__((ext_vector_type(8))) short bf16x8;
typedef __attribute__((ext_vector_type(4))) float f32x4;

#define MFMA(a, b, c) __builtin_amdgcn_mfma_f32_16x16x32_bf16(a, b, c, 0, 0, 0)

static __device__ __forceinline__ short f2bf(float f) {
    union { float f; unsigned u; } v; v.f = f;
    unsigned r = v.u + 0x7FFFu + ((v.u >> 16) & 1u);   // RNE
    return (short)(r >> 16);
}
static __device__ __forceinline__ float bf2f(short s) {
    union { unsigned u; float f; } v;
    v.u = ((unsigned)(unsigned short)s) << 16;
    return v.f;
}
static __device__ __forceinline__ unsigned pk2(float a, float b) {
    return (unsigned)(unsigned short)f2bf(a) |
           ((unsigned)(unsigned short)f2bf(b) << 16);
}

// ---------------------------------------------------------------------------
// K0a: bias gather -> bf16, layout [(w*6+h)][i*144+j].
// ---------------------------------------------------------------------------
__global__ __launch_bounds__(256)
void bias_k(const float* __restrict__ table, const int* __restrict__ pos_index,
            short* __restrict__ bias_bf) {
    const int t = blockIdx.x;                      // w*6+h, 0..383
    for (int e = threadIdx.x; e < N_TOK * N_TOK; e += 256) {
        int idx = pos_index[e];
        bias_bf[(long)t * (N_TOK * N_TOK) + e] = f2bf(table[(long)idx * 384 + t]);
    }
}

// K0b: f32 -> bf16 scalar copy (weights)
__global__ __launch_bounds__(256)
void cvt_k(const float* __restrict__ w, short* __restrict__ o, int n) {
    int i = blockIdx.x * 256 + threadIdx.x;
    if (i < n) o[i] = f2bf(w[i]);
}

// K0c: f32 -> bf16 vectorized (x, per chunk)
__global__ __launch_bounds__(256)
void cvtx_k(const float* __restrict__ x, short* __restrict__ xb, int n4) {
    int i = blockIdx.x * 256 + threadIdx.x;
    if (i < n4) {
        float4 f = ((const float4*)x)[i];
        short4 s = { f2bf(f.x), f2bf(f.y), f2bf(f.z), f2bf(f.w) };
        ((short4*)xb)[i] = s;
    }
}

// ---------------------------------------------------------------------------
// K1 (R4-proven): QKV GEMM. Block = (bwL, sel). W_sel in LDS (stride 200).
// A-frags from chunk-local x_bf global. 9 waves = 3mg x 3ng, wave tile 48x64.
// Epilogue: acc -> LDS [144][200] -> coalesced bf16x8 stores to
// qkv_ws[bwL][h][sel][row][e]. q pre-scaled.
// ---------------------------------------------------------------------------
__global__ __launch_bounds__(576)
void qkvs_k(const short* __restrict__ xb, const short* __restrict__ qkvw_bf,
            const float* __restrict__ qkv_b, short* __restrict__ qkv_out) {
    __shared__ short wlds[192 * 200];   // W_sel [oc][k]; reused for out staging

    const int sel = blockIdx.x % 3;
    const int bwL = blockIdx.x / 3;
    const int tid = threadIdx.x;

    for (int u = tid * 8; u < 192 * 192; u += 576 * 8) {
        int r = u / 192, c = u - r * 192;
        *(bf16x8*)&wlds[r * 200 + c] = *(const bf16x8*)&qkvw_bf[sel * 36864 + u];
    }
    __syncthreads();

    const int wid = tid >> 6, lane = tid & 63, lq = lane & 15, lg = lane >> 4;
    const int mg = wid / 3, ng = wid % 3;
    const short* xrow = xb + (long)bwL * N_TOK * DIM;

    f32x4 acc[3][4] = {};
    for (int ks = 0; ks < 6; ++ks) {
        const int k0 = ks * 32 + 8 * lg;
        bf16x8 av[3], bv[4];
        #pragma unroll
        for (int mt = 0; mt < 3; ++mt)
            av[mt] = *(const bf16x8*)&xrow[(mg * 48 + mt * 16 + lq) * DIM + k0];
        #pragma unroll
        for (int nt = 0; nt < 4; ++nt)
            bv[nt] = *(const bf16x8*)&wlds[(ng * 64 + nt * 16 + lq) * 200 + k0];
        #pragma unroll
        for (int mt = 0; mt < 3; ++mt)
            #pragma unroll
            for (int nt = 0; nt < 4; ++nt)
                acc[mt][nt] = MFMA(av[mt], bv[nt], acc[mt][nt]);
    }
    __syncthreads();   // done reading W -> reuse wlds

    const float scale = 0.17677669529663687f;   // 32^-0.5
    #pragma unroll
    for (int nt = 0; nt < 4; ++nt) {
        const int cd = ng * 64 + nt * 16 + lq;          // 0..191
        const float bb = qkv_b[sel * 192 + cd];
        #pragma unroll
        for (int mt = 0; mt < 3; ++mt)
            #pragma unroll
            for (int i = 0; i < 4; ++i) {
                int row = mg * 48 + mt * 16 + 4 * lg + i;
                float v = acc[mt][nt][i] + bb;
                if (sel == 0) v *= scale;
                wlds[row * 200 + cd] = f2bf(v);
            }
    }
    __syncthreads();

    short* ob = qkv_out + (long)bwL * 6 * 3 * 4608 + (long)sel * 4608;
    #pragma unroll
    for (int j = 0; j < 6; ++j) {
        int u = (j * 576 + tid) * 8;        // 0..27647
        int h = u / 4608, rem = u - h * 4608;
        int row = rem >> 5, e = rem & 31;
        *(bf16x8*)&ob[(long)h * 3 * 4608 + rem] =
            *(const bf16x8*)&wlds[row * 200 + h * 32 + e];
    }
}

// ---------------------------------------------------------------------------
// K2: attention. Block = bwL, 9 waves x 16 q-rows, loop over 6 heads.
// Swapped QK^T: lane holds S[k=nt*16+4lg+i][q=m0+lq]. Mask slice depends
// only on q-row -> preloaded ONCE into 9 float4 regs, reused across heads.
// Per head: v row-major -> vlds transposed; bias short4 loads; softmax with
// 2 shuffles; P packed -> per-wave LDS [16][40]; PV = mfma(V^T, P);
// coalesced short4 tmp writes.
// ---------------------------------------------------------------------------
__global__ __launch_bounds__(576)
void attn3_k(const short* __restrict__ qkv, const short* __restrict__ bias_bf,
             const float* __restrict__ mask, short* __restrict__ tmp, int bw0) {
    __shared__ short vlds[32 * 152];      //  9,728 B
    __shared__ short pws[9 * 16 * 40];    // 11,520 B

    const int bwL = blockIdx.x;
    const int bwG = bw0 + bwL;
    const int tid = threadIdx.x;
    const int lane = tid & 63, lq = lane & 15, lg = lane >> 4;
    const int wid = tid >> 6;
    const int q = wid * 16 + lq;          // this lane's query row
    const int w = bwG & 63;

    // ---- mask preload (head-invariant): 9 x float4 ----
    const float* mp = mask + (long)bwG * (N_TOK * N_TOK) + q * N_TOK + 4 * lg;
    float4 mreg[9];
    #pragma unroll
    for (int nt = 0; nt < 9; ++nt) mreg[nt] = *(const float4*)&mp[nt * 16];

    short* pw = pws + wid * 16 * 40;
    short* tb = tmp + (long)bwL * N_TOK * DIM + q * DIM;
    const f32x4 zf = {};
    const bf16x8 zb = {};

    #pragma unroll 1
    for (int h = 0; h < HEADS; ++h) {
        const short* qb = qkv + ((long)(bwL * 6 + h) * 3) * 4608;
        const short* kb = qb + 4608;
        const short* vb = qb + 9216;

        __syncthreads();   // previous head done with vlds
        {
            int j = tid >> 2, e0 = (tid & 3) * 8;
            bf16x8 vv = *(const bf16x8*)&vb[j * 32 + e0];
            #pragma unroll
            for (int u = 0; u < 8; ++u) vlds[(e0 + u) * 152 + j] = vv[u];
        }
        __syncthreads();

        // ---- QK^T (swapped: A=K tile, B=Q tile) ----
        bf16x8 bq = *(const bf16x8*)&qb[q * 32 + 8 * lg];
        f32x4 lgt[9];
        #pragma unroll
        for (int nt = 0; nt < 9; ++nt) {
            bf16x8 ak = *(const bf16x8*)&kb[(nt * 16 + lq) * 32 + 8 * lg];
            lgt[nt] = MFMA(ak, bq, zf);
        }

        // ---- + bias (short4) + mask (regs) ----
        const short* bp = bias_bf + (long)(w * 6 + h) * (N_TOK * N_TOK)
                        + q * N_TOK + 4 * lg;
        #pragma unroll
        for (int nt = 0; nt < 9; ++nt) {
            short4 bs = *(const short4*)&bp[nt * 16];
            lgt[nt][0] += bf2f(bs.x) + mreg[nt].x;
            lgt[nt][1] += bf2f(bs.y) + mreg[nt].y;
            lgt[nt][2] += bf2f(bs.z) + mreg[nt].z;
            lgt[nt][3] += bf2f(bs.w) + mreg[nt].w;
        }

        // ---- softmax over k (36 in-lane + xor16/xor32) ----
        float m = lgt[0][0];
        #pragma unroll
        for (int nt = 0; nt < 9; ++nt)
            #pragma unroll
            for (int i = 0; i < 4; ++i) m = fmaxf(m, lgt[nt][i]);
        m = fmaxf(m, __shfl_xor(m, 16));
        m = fmaxf(m, __shfl_xor(m, 32));
        float s = 0.f;
        #pragma unroll
        for (int nt = 0; nt < 9; ++nt)
            #pragma unroll
            for (int i = 0; i < 4; ++i) {
                float p = __expf(lgt[nt][i] - m);
                lgt[nt][i] = p;
                s += p;
            }
        s += __shfl_xor(s, 16);
        s += __shfl_xor(s, 32);
        const float inv = 1.f / s;

        // ---- PV: stream packed P through per-wave LDS [16][40] ----
        f32x4 o[2] = {};
        #pragma unroll
        for (int kt = 0; kt < 5; ++kt) {
            const int nt0 = 2 * kt;
            *(unsigned*)&pw[lq * 40 + 4 * lg]     = pk2(lgt[nt0][0], lgt[nt0][1]);
            *(unsigned*)&pw[lq * 40 + 4 * lg + 2] = pk2(lgt[nt0][2], lgt[nt0][3]);
            if (kt < 4) {
                const int nt1 = nt0 + 1;
                *(unsigned*)&pw[lq * 40 + 16 + 4 * lg]     = pk2(lgt[nt1][0], lgt[nt1][1]);
                *(unsigned*)&pw[lq * 40 + 16 + 4 * lg + 2] = pk2(lgt[nt1][2], lgt[nt1][3]);
            }
            bf16x8 bpf = *(const bf16x8*)&pw[lq * 40 + 8 * lg];
            #pragma unroll
            for (int et = 0; et < 2; ++et) {
                bf16x8 av = *(const bf16x8*)&vlds[(et * 16 + lq) * 152 + kt * 32 + 8 * lg];
                bf16x8 aa = av, bb = bpf;
                if (kt == 4 && lg >= 2) { aa = zb; bb = zb; }   // keys 144..159
                o[et] = MFMA(aa, bb, o[et]);
            }
        }

        // ---- write tmp[bwL][q][h*32 + e] (short4, 64B-sector aligned) ----
        #pragma unroll
        for (int et = 0; et < 2; ++et) {
            short4 sx = { f2bf(o[et][0] * inv), f2bf(o[et][1] * inv),
                          f2bf(o[et][2] * inv), f2bf(o[et][3] * inv) };
            *(short4*)&tb[h * 32 + et * 16 + 4 * lg] = sx;
        }
    }
}

// ---------------------------------------------------------------------------
// K3: output projection. Block = (bwL, m-third), 3 waves, wave = 16 rows.
// ---------------------------------------------------------------------------
__global__ __launch_bounds__(192)
void proj_k(const short* __restrict__ tmp, const short* __restrict__ pwt,
            const float* __restrict__ proj_b, float* __restrict__ out, int bw0) {
    const int bid = blockIdx.x;
    const int mthird = bid % 3;
    const int bwL = bid / 3;
    const int bwG = bw0 + bwL;
    const int tid = threadIdx.x;
    const int wid = tid >> 6, lane = tid & 63, lq = lane & 15, lg = lane >> 4;
    const int m0 = (mthird * 3 + wid) * 16;
    const short* tb = tmp + (long)bwL * N_TOK * DIM;

    f32x4 acc[12] = {};
    for (int ks = 0; ks < 6; ++ks) {
        const int k0 = ks * 32 + 8 * lg;
        bf16x8 a = *(const bf16x8*)&tb[(m0 + lq) * DIM + k0];
        #pragma unroll
        for (int nt = 0; nt < 12; ++nt) {
            bf16x8 b = *(const bf16x8*)&pwt[(nt * 16 + lq) * DIM + k0];
            acc[nt] = MFMA(a, b, acc[nt]);
        }
    }
    float* ob = out + (long)bwG * N_TOK * DIM;
    #pragma unroll
    for (int nt = 0; nt < 12; ++nt) {
        float pb = proj_b[nt * 16 + lq];
        #pragma unroll
        for (int i = 0; i < 4; ++i)
            ob[(m0 + 4 * lg + i) * DIM + nt * 16 + lq] = acc[nt][i] + pb;
    }
}

// ---------------------------------------------------------------------------
extern "C" void kernel_launch(void* const* d_in, const int* in_sizes, int n_in,
                              void* d_out, int out_size, void* d_ws, size_t ws_size,
                              hipStream_t stream) {
    const float* x        = (const float*)d_in[0];
    const float* mask     = (const float*)d_in[1];
    const float* qkv_w    = (const float*)d_in[2];
    const float* qkv_b    = (const float*)d_in[3];
    const float* table    = (const float*)d_in[4];
    const float* proj_w   = (const float*)d_in[5];
    const float* proj_b   = (const float*)d_in[6];
    const int*   pos_index= (const int*)d_in[7];
    float* out = (float*)d_out;

    // ws layout (bf16 shorts), total 122.4 MB (== R4's proven footprint):
    //  bias_bf  [384][144*144]            15.93 MB
    //  projw_bf [192*192]                  0.07 MB
    //  qkvw_bf  [576*192]                  0.22 MB
    //  xbf/tmp  [CHUNK x 144 x 192]       26.54 MB (xbf dead after qkvs ->
    //                                               tmp aliases it)
    //  qkv_ws   [CHUNK*6 x 3 x 144 x 32]  79.63 MB (per chunk)
    short* bias_bf  = (short*)d_ws;
    short* projw_bf = bias_bf + (size_t)384 * N_TOK * N_TOK;
    short* qkvw_bf  = projw_bf + 36864;
    short* xbf_ws   = qkvw_bf + 110592;
    short* tmp_ws   = xbf_ws;                       // alias (see above)
    short* qkv_ws   = xbf_ws + (size_t)CHUNK * N_TOK * DIM;

    bias_k<<<384, 256, 0, stream>>>(table, pos_index, bias_bf);
    cvt_k<<<144, 256, 0, stream>>>(proj_w, projw_bf, DIM * DIM);
    cvt_k<<<432, 256, 0, stream>>>(qkv_w, qkvw_bf, 3 * DIM * DIM);

    const int n4 = CHUNK * N_TOK * DIM / 4;   // 3,317,760
    for (int c = 0; c < 2; ++c) {
        const int bw0 = c * CHUNK;
        cvtx_k<<<(n4 + 255) / 256, 256, 0, stream>>>(
            x + (long)bw0 * N_TOK * DIM, xbf_ws, n4);
        qkvs_k<<<CHUNK * 3, 576, 0, stream>>>(xbf_ws, qkvw_bf, qkv_b, qkv_ws);
        attn3_k<<<CHUNK, 576, 0, stream>>>(qkv_ws, bias_bf, mask, tmp_ws, bw0);
        proj_k<<<CHUNK * 3, 192, 0, stream>>>(tmp_ws, projw_bf, proj_b, out, bw0);
    }
}